// Round 17
// baseline (2391.562 us; speedup 1.0000x reference)
//
#include <hip/hip_runtime.h>
#include <hip/hip_bf16.h>
#include <math.h>

typedef __attribute__((ext_vector_type(8))) short short8;
typedef __attribute__((ext_vector_type(4))) short short4v;
typedef __attribute__((ext_vector_type(4))) float f32x4;

#define MFMA16 __builtin_amdgcn_mfma_f32_16x16x32_bf16
#define GLOAD(dst, src) __builtin_amdgcn_global_load_lds( \
    (const __attribute__((address_space(1))) void*)(src), \
    (__attribute__((address_space(3))) void*)(dst), 16, 0, 0)

__device__ __forceinline__ short f2bf(float f){
  unsigned u = __float_as_uint(f);
  u = (u + 0x7FFFu + ((u >> 16) & 1u)) >> 16;
  return (short)u;
}

// K-panel-packed layout: [m>>8][k>>5][m&255][k&31] (16KB contiguous per (mtile,ktile))
__device__ __forceinline__ size_t pidx(int r, int k, int K){
  return ((size_t)((r >> 8) * (K >> 5) + (k >> 5)) * 256 + (r & 255)) * 32 + (k & 31);
}

__device__ __forceinline__ float gelu_phi(float g){
  float ax = fabsf(g) * 0.70710678118f;
  float t  = 1.f / (1.f + 0.3275911f * ax);
  float pp = ((((1.061405429f * t - 1.453152027f) * t + 1.421413741f) * t
               - 0.284496736f) * t + 0.254829592f) * t;
  float e  = 1.f - pp * __expf(-ax * ax);
  return 0.5f + copysignf(0.5f, g) * e;
}

// ---------------- weight prep (cast + pack, x4 vectorized) ----------------
__global__ void cast_pack_kernel(const float* __restrict__ s, short* __restrict__ d,
                                 int NROW, int K){
  long i = ((long)blockIdx.x * 256 + threadIdx.x) * 4;   // over 4*NROW*K
  long per = (long)NROW * K;
  int l = (int)(i / per); long rem = i - (long)l * per;
  int r = (int)(rem / K), c = (int)(rem - (long)r * K);
  float4 v = *(const float4*)(s + i);
  short4v o; o[0] = f2bf(v.x); o[1] = f2bf(v.y); o[2] = f2bf(v.z); o[3] = f2bf(v.w);
  *(short4v*)(d + (size_t)l * per + pidx(r, c, K)) = o;
}

__global__ void w1p_kernel(const float* __restrict__ s, short* __restrict__ d){
  long i = ((long)blockIdx.x * 256 + threadIdx.x) * 4;   // 4*2816*512
  int c  = (int)(i & 511);
  long rl = i >> 9;
  int r  = (int)(rl % 2816);
  int l  = (int)(rl / 2816);
  int g  = r >> 5, sfx = r & 31;
  int j  = g * 16 + (sfx & 15);
  short4v o;
  if (j < 1365){
    int sr = (sfx < 16) ? j : 1365 + j;
    float4 v = *(const float4*)(s + ((size_t)l * 2730 + sr) * 512 + c);
    o[0] = f2bf(v.x); o[1] = f2bf(v.y); o[2] = f2bf(v.z); o[3] = f2bf(v.w);
  } else {
    o[0] = 0; o[1] = 0; o[2] = 0; o[3] = 0;
  }
  *(short4v*)(d + (size_t)l * 2816 * 512 + pidx(r, c, 512)) = o;
}

__global__ void w2p_kernel(const float* __restrict__ s, short* __restrict__ d){
  long i = ((long)blockIdx.x * 256 + threadIdx.x) * 4;   // 4*512*1408
  int c = (int)(i % 1408);
  long rr = i / 1408;
  int l = (int)(rr >> 9), row = (int)(rr & 511);
  short4v o;
  #pragma unroll
  for (int e = 0; e < 4; e++)
    o[e] = (c + e < 1365) ? f2bf(s[rr * 1365 + c + e]) : (short)0;
  *(short4v*)(d + (size_t)l * 512 * 1408 + pidx(row, c, 1408)) = o;
}

// ---------------- embedding (packed bf16 out) ----------------
__global__ void embed_kernel(const float* __restrict__ x, const float* __restrict__ w,
                             const float* __restrict__ bias, float* __restrict__ hf,
                             short* __restrict__ hb){
  long i = ((long)blockIdx.x * 256 + threadIdx.x) * 8;
  long row = i >> 9; int e = (int)(i & 511);
  float xv = x[row];
  float4 w0 = *(const float4*)(w + e),    w1 = *(const float4*)(w + e + 4);
  float4 b0 = *(const float4*)(bias + e), b1 = *(const float4*)(bias + e + 4);
  float4 o0, o1;
  o0.x = xv*w0.x+b0.x; o0.y = xv*w0.y+b0.y; o0.z = xv*w0.z+b0.z; o0.w = xv*w0.w+b0.w;
  o1.x = xv*w1.x+b1.x; o1.y = xv*w1.y+b1.y; o1.z = xv*w1.z+b1.z; o1.w = xv*w1.w+b1.w;
  *(float4*)(hf + i) = o0; *(float4*)(hf + i + 4) = o1;
  short8 hv;
  hv[0]=f2bf(o0.x); hv[1]=f2bf(o0.y); hv[2]=f2bf(o0.z); hv[3]=f2bf(o0.w);
  hv[4]=f2bf(o1.x); hv[5]=f2bf(o1.y); hv[6]=f2bf(o1.z); hv[7]=f2bf(o1.w);
  *(short8*)(hb + pidx((int)row, e, 512)) = hv;
}

// ---------------- 256x256 GEMM (frozen): A+B LDS ring-4, packed staging ----------------
// Measured plateau 143-149us FF1 (~660 TF) across 8 structural variants;
// matches learn_hip 2-phase plain-HIP ceiling (m230/m248: 655-682 TF).
// EPI: 1 Cres+=acc; 2 Cres+=acc & packed bf16(K=512); 3 GEGLU->packed(K=1408);
//      4 head-major bf16 store for QKV.
template<int EPI>
__global__ __launch_bounds__(1024, 4)
void gemm_pk(const short* __restrict__ A, const short* __restrict__ B, int K,
             float* __restrict__ Cres, short* __restrict__ Cbf, int ldcb)
{
  __shared__ short As[4][256][32];
  __shared__ short Bs[4][256][32];
  char* smA = (char*)As; char* smB = (char*)Bs;
  const int tid = threadIdx.x, lane = tid & 63, w = tid >> 6;
  const int wm = w >> 2, wn = w & 3;
  const int NT = K >> 5;
  const int nwg = gridDim.x * gridDim.y;
  const int f = blockIdx.y * gridDim.x + blockIdx.x;
  const int sw = (f & 7) * (nwg >> 3) + (f >> 3);
  const long tm = (long)(sw / gridDim.x) * 256;
  const long tn = (long)(sw % gridDim.x) * 256;

  const int srow = tid >> 2;
  const int sc   = (tid & 3) ^ ((srow >> 1) & 3);
  const short* aS = A + ((size_t)(tm >> 8) * NT * 256 + srow) * 32 + sc * 8;
  const short* bS = B + ((size_t)(tn >> 8) * NT * 256 + srow) * 32 + sc * 8;
  const int ldsW = w * 1024;

  f32x4 acc[4][4];
  #pragma unroll
  for (int i = 0; i < 4; i++)
    #pragma unroll
    for (int j = 0; j < 4; j++) acc[i][j] = (f32x4){0.f,0.f,0.f,0.f};

  const int rA = wm * 64 + (lane & 15);
  const int rB = wn * 64 + (lane & 15);
  const int abase = rA * 64 + (((lane >> 4) ^ ((rA >> 1) & 3)) * 16);
  const int bbase = rB * 64 + (((lane >> 4) ^ ((rB >> 1) & 3)) * 16);

  GLOAD(smA + 0 + ldsW, aS);             GLOAD(smB + 0 + ldsW, bS);
  GLOAD(smA + 16384 + ldsW, aS + 8192);  GLOAD(smB + 16384 + ldsW, bS + 8192);
  GLOAD(smA + 32768 + ldsW, aS + 16384); GLOAD(smB + 32768 + ldsW, bS + 16384);
  asm volatile("s_waitcnt vmcnt(4)" ::: "memory");
  __builtin_amdgcn_s_barrier();

  for (int t = 0; t < NT; ++t){
    const int cur = (t & 3) * 16384;
    const int stb = ((t + 3) & 3) * 16384;
    const size_t ko = (size_t)(t + 3) * 8192;
    if (t + 3 < NT){ GLOAD(smA + stb + ldsW, aS + ko); GLOAD(smB + stb + ldsW, bS + ko); }
    short8 a[4], bb[4];
    #pragma unroll
    for (int ni = 0; ni < 4; ni++)
      bb[ni] = *(const short8*)(smB + cur + bbase + ni * 1024);
    #pragma unroll
    for (int q = 0; q < 4; q++)
      a[q] = *(const short8*)(smA + cur + abase + q * 1024);
    #pragma unroll
    for (int q = 0; q < 4; q++)
      #pragma unroll
      for (int ni = 0; ni < 4; ni++)
        acc[q][ni] = MFMA16(a[q], bb[ni], acc[q][ni], 0, 0, 0);
    if      (t + 3 < NT) asm volatile("s_waitcnt vmcnt(4)" ::: "memory");
    else if (t + 2 < NT) asm volatile("s_waitcnt vmcnt(2)" ::: "memory");
    else if (t + 1 < NT) asm volatile("s_waitcnt vmcnt(0)" ::: "memory");
    __builtin_amdgcn_s_barrier();
  }

  #pragma unroll
  for (int mi = 0; mi < 4; mi++){
    if (EPI == 3){
      #pragma unroll
      for (int p = 0; p < 2; p++)
        #pragma unroll
        for (int v = 0; v < 4; v++){
          int row = (int)(tm + wm * 64 + mi * 16 + (lane >> 4) * 4 + v);
          int col = (int)((tn >> 1) + wn * 32 + p * 16 + (lane & 15));
          float u = acc[mi][2*p][v], g = acc[mi][2*p+1][v];
          Cbf[pidx(row, col, 1408)] = f2bf(u * g * gelu_phi(g));
        }
    } else {
      #pragma unroll
      for (int ni = 0; ni < 4; ni++)
        #pragma unroll
        for (int v = 0; v < 4; v++){
          int row = (int)(tm + wm * 64 + mi * 16 + (lane >> 4) * 4 + v);
          int col = (int)(tn + wn * 64 + ni * 16 + (lane & 15));
          float x = acc[mi][ni][v];
          if (EPI == 4){
            int hd = col >> 6, d = col & 63;
            Cbf[((size_t)hd * 32768 + row) * 64 + d] = f2bf(x);
          } else if (EPI == 1){
            Cres[(long)row * 512 + col] = x + Cres[(long)row * 512 + col];
          } else {
            float rr = x + Cres[(long)row * 512 + col];
            Cres[(long)row * 512 + col] = rr;
            Cbf[pidx(row, col, 512)] = f2bf(rr);
          }
        }
    }
  }
}

// ---------------- local attention (R16 body + Ps aliased onto dead Ks -> 3 blocks/CU) ----
// LDS 50,176 B: Ks 16K (reused as waves 0-1's P after QK^T) + Vt 17.4K + Ps2 16K
// (waves 2-3's P). New barrier between QK^T and P-stores: all waves' Ks reads
// drain (barrier implies lgkmcnt(0)) before any aliased P write; PV reads only
// own-wave P (ordered by existing pre-PV barrier); loop-top barrier protects
// next chunk's K restage. Guards block-uniform -> no barrier divergence.
__global__ __launch_bounds__(256, 3)
void attn_kernel(const short* __restrict__ qkv, short* __restrict__ o)
{
  __shared__ short Ks[128 * 64];       // 16 KB: K during QK^T, then P of waves 0-1
  __shared__ short Vt[64 * 136];       // 17.4 KB
  __shared__ short Ps2[2 * 32 * 128];  // 16 KB: P of waves 2-3
  char* smK = (char*)Ks;
  const int fdec = (blockIdx.x & 7) * 256 + (blockIdx.x >> 3);
  const int win = fdec & 31, hh = (fdec >> 5) & 7, b = fdec >> 8;
  const int tid = threadIdx.x, lane = tid & 63, w = tid >> 6;
  const long qrow0 = (long)b * 4096 + (long)win * 128;
  const short* Qb = qkv + (size_t)hh * 2097152;
  const short* Kb = qkv + (size_t)(8 + hh) * 2097152;
  const short* Vb = qkv + (size_t)(16 + hh) * 2097152;

  short8 qf[2][2];
  #pragma unroll
  for (int i = 0; i < 2; i++)
    #pragma unroll
    for (int kk = 0; kk < 2; kk++)
      qf[i][kk] = *(const short8*)(Qb + (qrow0 + w * 32 + i * 16 + (lane & 15)) * 64
                                   + kk * 32 + (lane >> 4) * 8);

  f32x4 oacc[2][4];
  #pragma unroll
  for (int i = 0; i < 2; i++)
    #pragma unroll
    for (int j = 0; j < 4; j++) oacc[i][j] = (f32x4){0.f,0.f,0.f,0.f};
  float rs[2][4];
  #pragma unroll
  for (int i = 0; i < 2; i++)
    #pragma unroll
    for (int v = 0; v < 4; v++) rs[i][v] = 0.f;

  const int row_s = tid >> 3;
  const int c_s   = tid & 7;
  const int schK  = (tid & 7) ^ ((tid >> 3) & 7);
  char* myPs = (w < 2) ? (smK + w * 8192) : ((char*)Ps2 + (w - 2) * 8192);

  for (int cc = 0; cc < 3; cc++){
    int kw = win - 1 + cc;
    if (kw < 0 || kw >= 32) continue;        // uniform per block
    const long krow0 = (long)b * 4096 + (long)kw * 128;
    __syncthreads();                          // prior chunk's P/Vt reads done
    const short* srcK = Kb + (krow0 + row_s) * 64 + schK * 8;
    const short* srcV = Vb + (krow0 + row_s) * 64 + c_s * 8;
    #pragma unroll
    for (int r = 0; r < 4; r++){
      GLOAD(smK + w * 1024 + r * 4096, srcK + (size_t)r * 32 * 64);
      short8 vv = *(const short8*)(srcV + (size_t)r * 32 * 64);
      int row = row_s + r * 32;
      #pragma unroll
      for (int e = 0; e < 8; e++) Vt[(c_s * 8 + e) * 136 + row] = vv[e];
    }
    __syncthreads();

    f32x4 sacc[2][8];
    #pragma unroll
    for (int i = 0; i < 2; i++)
      #pragma unroll
      for (int j = 0; j < 8; j++) sacc[i][j] = (f32x4){0.f,0.f,0.f,0.f};
    #pragma unroll
    for (int kk = 0; kk < 2; kk++){
      short8 bbk[8];
      int ac = (kk * 32 + (lane >> 4) * 8) * 2;
      #pragma unroll
      for (int j = 0; j < 8; j++){
        int br = j * 16 + (lane & 15);
        bbk[j] = *(const short8*)(smK + ((br * 128 + ac) ^ ((br & 7) << 4)));
      }
      #pragma unroll
      for (int i = 0; i < 2; i++)
        #pragma unroll
        for (int j = 0; j < 8; j++)
          sacc[i][j] = MFMA16(qf[i][kk], bbk[j], sacc[i][j], 0, 0, 0);
    }
    __syncthreads();   // ALL waves' Ks reads complete -> safe to alias Ks as P

    float psum[2][4];
    #pragma unroll
    for (int i = 0; i < 2; i++)
      #pragma unroll
      for (int v = 0; v < 4; v++) psum[i][v] = 0.f;
    #pragma unroll
    for (int i = 0; i < 2; i++)
      #pragma unroll
      for (int j = 0; j < 8; j++)
        #pragma unroll
        for (int v = 0; v < 4; v++){
          float p = __expf(0.125f * sacc[i][j][v]);
          psum[i][v] += p;
          int prow = i * 16 + (lane >> 4) * 4 + v;
          int pcb  = (j * 16 + (lane & 15)) * 2;
          *(short*)(myPs + ((prow * 256 + pcb) ^ ((prow & 7) << 4))) = f2bf(p);
        }
    #pragma unroll
    for (int i = 0; i < 2; i++)
      #pragma unroll
      for (int v = 0; v < 4; v++){
        float s = psum[i][v];
        s += __shfl_xor(s, 1); s += __shfl_xor(s, 2);
        s += __shfl_xor(s, 4); s += __shfl_xor(s, 8);
        rs[i][v] += s;
      }
    __syncthreads();

    #pragma unroll
    for (int kk = 0; kk < 4; kk++){
      short8 pa[2], vb[4];
      int kb = (kk * 32 + (lane >> 4) * 8) * 2;
      #pragma unroll
      for (int i = 0; i < 2; i++){
        int pr = i * 16 + (lane & 15);
        pa[i] = *(const short8*)(myPs + ((pr * 256 + kb) ^ ((pr & 7) << 4)));
      }
      #pragma unroll
      for (int j = 0; j < 4; j++){
        int vr = j * 16 + (lane & 15);
        vb[j] = *(const short8*)((char*)Vt + (vr * 272 + kb));
      }
      #pragma unroll
      for (int i = 0; i < 2; i++)
        #pragma unroll
        for (int j = 0; j < 4; j++)
          oacc[i][j] = MFMA16(pa[i], vb[j], oacc[i][j], 0, 0, 0);
    }
  }

  #pragma unroll
  for (int i = 0; i < 2; i++)
    #pragma unroll
    for (int j = 0; j < 4; j++)
      #pragma unroll
      for (int v = 0; v < 4; v++){
        int row = (int)(qrow0 + w * 32 + i * 16 + (lane >> 4) * 4 + v);
        int col = hh * 64 + j * 16 + (lane & 15);
        o[pidx(row, col, 512)] = f2bf(oacc[i][j][v] / rs[i][v]);
      }
}

// ---------------- layernorm (packed bf16 out) ----------------
__global__ __launch_bounds__(256)
void ln_kernel(const float* __restrict__ h, const float* __restrict__ g,
               const float* __restrict__ be, short* __restrict__ y)
{
  long row = (long)blockIdx.x * 4 + (threadIdx.x >> 6);
  int lane = threadIdx.x & 63;
  const float* x = h + row * 512 + lane * 8;
  float4 a0 = *(const float4*)x;
  float4 a1 = *(const float4*)(x + 4);
  float v[8] = {a0.x, a0.y, a0.z, a0.w, a1.x, a1.y, a1.z, a1.w};
  float s = 0.f, sq = 0.f;
  #pragma unroll
  for (int j = 0; j < 8; j++){ s += v[j]; sq += v[j] * v[j]; }
  #pragma unroll
  for (int m = 1; m <= 32; m <<= 1){ s += __shfl_xor(s, m); sq += __shfl_xor(sq, m); }
  float mu = s * (1.f / 512.f);
  float var = sq * (1.f / 512.f) - mu * mu;
  float rstd = rsqrtf(var + 1e-5f);
  short8 yv;
  #pragma unroll
  for (int j = 0; j < 8; j++){
    int c = lane * 8 + j;
    yv[j] = f2bf((v[j] - mu) * rstd * g[c] + be[c]);
  }
  *(short8*)(y + pidx((int)row, lane * 8, 512)) = yv;
}

// ---------------- mean pool + classifier ----------------
__global__ void pool_partial(const float* __restrict__ h, float* __restrict__ part){
  int b = blockIdx.x, ch = blockIdx.y, t = threadIdx.x;
  float s0 = 0.f, s1 = 0.f;
  const float* base = h + ((long)b * 4096 + ch * 128) * 512;
  for (int n = 0; n < 128; n++){
    s0 += base[(long)n * 512 + t];
    s1 += base[(long)n * 512 + t + 256];
  }
  part[((b * 32 + ch) * 512) + t] = s0;
  part[((b * 32 + ch) * 512) + t + 256] = s1;
}

__global__ void pool_proj(const float* __restrict__ part, const float* __restrict__ pw,
                          const float* __restrict__ pb, float* __restrict__ out){
  __shared__ float pooled[512];
  __shared__ float red[4];
  int b = blockIdx.x, t = threadIdx.x;
  int lane = t & 63, w = t >> 6;
  float s0 = 0.f, s1 = 0.f;
  for (int ch = 0; ch < 32; ch++){
    s0 += part[((b * 32 + ch) * 512) + t];
    s1 += part[((b * 32 + ch) * 512) + t + 256];
  }
  pooled[t] = s0 * (1.f / 4096.f);
  pooled[t + 256] = s1 * (1.f / 4096.f);
  __syncthreads();
  for (int cls = 0; cls < 10; cls++){
    float p = pooled[t] * pw[cls * 512 + t] + pooled[t + 256] * pw[cls * 512 + t + 256];
    p += __shfl_xor(p, 1); p += __shfl_xor(p, 2); p += __shfl_xor(p, 4);
    p += __shfl_xor(p, 8); p += __shfl_xor(p, 16); p += __shfl_xor(p, 32);
    if (lane == 0) red[w] = p;
    __syncthreads();
    if (t == 0) out[b * 10 + cls] = red[0] + red[1] + red[2] + red[3] + pb[cls];
    __syncthreads();
  }
}

extern "C" void kernel_launch(void* const* d_in, const int* in_sizes, int n_in,
                              void* d_out, int out_size, void* d_ws, size_t ws_size,
                              hipStream_t stream)
{
  const float* x      = (const float*)d_in[0];
  const float* lin_w  = (const float*)d_in[1];
  const float* lin_b  = (const float*)d_in[2];
  const float* qkvw_f = (const float*)d_in[3];
  const float* outw_f = (const float*)d_in[4];
  const float* lng    = (const float*)d_in[5];
  const float* lnb    = (const float*)d_in[6];
  const float* w1_f   = (const float*)d_in[7];
  const float* w2_f   = (const float*)d_in[8];
  const float* projw  = (const float*)d_in[9];
  const float* projb  = (const float*)d_in[10];
  float* out = (float*)d_out;

  char* ws = (char*)d_ws;
  float* hf32 = (float*)(ws);
  short* abuf = (short*)(ws + 67108864);
  short* qkvb = (short*)(ws + 100663296);
  short* gbuf = qkvb;
  short* obuf = (short*)(ws + 201326592);
  float* part = (float*)(ws + 234881024);
  short* wqkv = (short*)(ws + 235405312);
  short* wout = (short*)(ws + 247988224);
  short* w1p  = (short*)(ws + 250085376);
  short* w2p  = (short*)(ws + 261619712);

  cast_pack_kernel<<<3072, 256, 0, stream>>>(qkvw_f, wqkv, 1536, 512);
  cast_pack_kernel<<<1024, 256, 0, stream>>>(outw_f, wout, 512, 512);
  w1p_kernel<<<5632, 256, 0, stream>>>(w1_f, w1p);
  w2p_kernel<<<2816, 256, 0, stream>>>(w2_f, w2p);
  embed_kernel<<<8192, 256, 0, stream>>>(x, lin_w, lin_b, hf32, abuf);

  for (int l = 0; l < 4; l++){
    gemm_pk<4><<<dim3(6, 128), 1024, 0, stream>>>(abuf, wqkv + (size_t)l * 1536 * 512, 512,
                                                  nullptr, qkvb, 0);
    attn_kernel<<<2048, 256, 0, stream>>>(qkvb, obuf);
    gemm_pk<1><<<dim3(2, 128), 1024, 0, stream>>>(obuf, wout + (size_t)l * 512 * 512, 512,
                                                  hf32, nullptr, 0);
    ln_kernel<<<8192, 256, 0, stream>>>(hf32, lng + l * 512, lnb + l * 512, abuf);
    gemm_pk<3><<<dim3(11, 128), 1024, 0, stream>>>(abuf, w1p + (size_t)l * 2816 * 512, 512,
                                                   nullptr, gbuf, 1408);
    gemm_pk<2><<<dim3(2, 128), 1024, 0, stream>>>(gbuf, w2p + (size_t)l * 512 * 1408, 1408,
                                                  hf32, abuf, 512);
  }
  pool_partial<<<dim3(8, 32), 256, 0, stream>>>(hf32, part);
  pool_proj<<<8, 256, 0, stream>>>(part, projw, projb, out);
}

// Round 18
// 1784.067 us; speedup vs baseline: 1.3405x; 1.3405x over previous
//
#include <hip/hip_runtime.h>
#include <hip/hip_bf16.h>
#include <math.h>

typedef __attribute__((ext_vector_type(8))) short short8;
typedef __attribute__((ext_vector_type(4))) short short4v;
typedef __attribute__((ext_vector_type(4))) float f32x4;

#define MFMA16 __builtin_amdgcn_mfma_f32_16x16x32_bf16
#define GLOAD(dst, src) __builtin_amdgcn_global_load_lds( \
    (const __attribute__((address_space(1))) void*)(src), \
    (__attribute__((address_space(3))) void*)(dst), 16, 0, 0)

__device__ __forceinline__ short f2bf(float f){
  unsigned u = __float_as_uint(f);
  u = (u + 0x7FFFu + ((u >> 16) & 1u)) >> 16;
  return (short)u;
}

// K-panel-packed layout: [m>>8][k>>5][m&255][k&31] (16KB contiguous per (mtile,ktile))
__device__ __forceinline__ size_t pidx(int r, int k, int K){
  return ((size_t)((r >> 8) * (K >> 5) + (k >> 5)) * 256 + (r & 255)) * 32 + (k & 31);
}

__device__ __forceinline__ float gelu_phi(float g){
  float ax = fabsf(g) * 0.70710678118f;
  float t  = 1.f / (1.f + 0.3275911f * ax);
  float pp = ((((1.061405429f * t - 1.453152027f) * t + 1.421413741f) * t
               - 0.284496736f) * t + 0.254829592f) * t;
  float e  = 1.f - pp * __expf(-ax * ax);
  return 0.5f + copysignf(0.5f, g) * e;
}

// ---------------- weight prep (cast + pack, x4 vectorized) ----------------
// c%4==0 and c..c+3 stay inside one 32-k panel group -> 4 contiguous shorts.
__global__ void cast_pack_kernel(const float* __restrict__ s, short* __restrict__ d,
                                 int NROW, int K){
  long i = ((long)blockIdx.x * 256 + threadIdx.x) * 4;   // over 4*NROW*K
  long per = (long)NROW * K;
  int l = (int)(i / per); long rem = i - (long)l * per;
  int r = (int)(rem / K), c = (int)(rem - (long)r * K);
  float4 v = *(const float4*)(s + i);
  short4v o; o[0] = f2bf(v.x); o[1] = f2bf(v.y); o[2] = f2bf(v.z); o[3] = f2bf(v.w);
  *(short4v*)(d + (size_t)l * per + pidx(r, c, K)) = o;
}

// ff_w1 (4,2730,512) -> packed W1p (4,2816,512), u/gate 16-row interleave
__global__ void w1p_kernel(const float* __restrict__ s, short* __restrict__ d){
  long i = ((long)blockIdx.x * 256 + threadIdx.x) * 4;   // 4*2816*512
  int c  = (int)(i & 511);
  long rl = i >> 9;
  int r  = (int)(rl % 2816);
  int l  = (int)(rl / 2816);
  int g  = r >> 5, sfx = r & 31;
  int j  = g * 16 + (sfx & 15);
  short4v o;
  if (j < 1365){
    int sr = (sfx < 16) ? j : 1365 + j;
    float4 v = *(const float4*)(s + ((size_t)l * 2730 + sr) * 512 + c);
    o[0] = f2bf(v.x); o[1] = f2bf(v.y); o[2] = f2bf(v.z); o[3] = f2bf(v.w);
  } else {
    o[0] = 0; o[1] = 0; o[2] = 0; o[3] = 0;
  }
  *(short4v*)(d + (size_t)l * 2816 * 512 + pidx(r, c, 512)) = o;
}

// ff_w2 (4,512,1365) -> packed W2p (4,512,1408), K zero-padded (guard 1365 boundary)
__global__ void w2p_kernel(const float* __restrict__ s, short* __restrict__ d){
  long i = ((long)blockIdx.x * 256 + threadIdx.x) * 4;   // 4*512*1408
  int c = (int)(i % 1408);
  long rr = i / 1408;
  int l = (int)(rr >> 9), row = (int)(rr & 511);
  short4v o;
  #pragma unroll
  for (int e = 0; e < 4; e++)
    o[e] = (c + e < 1365) ? f2bf(s[rr * 1365 + c + e]) : (short)0;
  *(short4v*)(d + (size_t)l * 512 * 1408 + pidx(row, c, 1408)) = o;
}

// ---------------- embedding (packed bf16 out) ----------------
__global__ void embed_kernel(const float* __restrict__ x, const float* __restrict__ w,
                             const float* __restrict__ bias, float* __restrict__ hf,
                             short* __restrict__ hb){
  long i = ((long)blockIdx.x * 256 + threadIdx.x) * 8;
  long row = i >> 9; int e = (int)(i & 511);
  float xv = x[row];
  float4 w0 = *(const float4*)(w + e),    w1 = *(const float4*)(w + e + 4);
  float4 b0 = *(const float4*)(bias + e), b1 = *(const float4*)(bias + e + 4);
  float4 o0, o1;
  o0.x = xv*w0.x+b0.x; o0.y = xv*w0.y+b0.y; o0.z = xv*w0.z+b0.z; o0.w = xv*w0.w+b0.w;
  o1.x = xv*w1.x+b1.x; o1.y = xv*w1.y+b1.y; o1.z = xv*w1.z+b1.z; o1.w = xv*w1.w+b1.w;
  *(float4*)(hf + i) = o0; *(float4*)(hf + i + 4) = o1;
  short8 hv;
  hv[0]=f2bf(o0.x); hv[1]=f2bf(o0.y); hv[2]=f2bf(o0.z); hv[3]=f2bf(o0.w);
  hv[4]=f2bf(o1.x); hv[5]=f2bf(o1.y); hv[6]=f2bf(o1.z); hv[7]=f2bf(o1.w);
  *(short8*)(hb + pidx((int)row, e, 512)) = hv;
}

// ---------------- 256x256 GEMM (frozen): A+B LDS ring-4, packed staging ----------------
// Measured plateau 143-149us FF1 (~660 TF) across 8 structural variants;
// matches learn_hip 2-phase plain-HIP ceiling (m230/m248: 655-682 TF).
// EPI: 1 Cres+=acc; 2 Cres+=acc & packed bf16(K=512); 3 GEGLU->packed(K=1408);
//      4 head-major bf16 store for QKV.
template<int EPI>
__global__ __launch_bounds__(1024, 4)
void gemm_pk(const short* __restrict__ A, const short* __restrict__ B, int K,
             float* __restrict__ Cres, short* __restrict__ Cbf, int ldcb)
{
  __shared__ short As[4][256][32];
  __shared__ short Bs[4][256][32];
  char* smA = (char*)As; char* smB = (char*)Bs;
  const int tid = threadIdx.x, lane = tid & 63, w = tid >> 6;
  const int wm = w >> 2, wn = w & 3;
  const int NT = K >> 5;
  const int nwg = gridDim.x * gridDim.y;
  const int f = blockIdx.y * gridDim.x + blockIdx.x;
  const int sw = (f & 7) * (nwg >> 3) + (f >> 3);
  const long tm = (long)(sw / gridDim.x) * 256;
  const long tn = (long)(sw % gridDim.x) * 256;

  const int srow = tid >> 2;
  const int sc   = (tid & 3) ^ ((srow >> 1) & 3);
  const short* aS = A + ((size_t)(tm >> 8) * NT * 256 + srow) * 32 + sc * 8;
  const short* bS = B + ((size_t)(tn >> 8) * NT * 256 + srow) * 32 + sc * 8;
  const int ldsW = w * 1024;

  f32x4 acc[4][4];
  #pragma unroll
  for (int i = 0; i < 4; i++)
    #pragma unroll
    for (int j = 0; j < 4; j++) acc[i][j] = (f32x4){0.f,0.f,0.f,0.f};

  const int rA = wm * 64 + (lane & 15);
  const int rB = wn * 64 + (lane & 15);
  const int abase = rA * 64 + (((lane >> 4) ^ ((rA >> 1) & 3)) * 16);
  const int bbase = rB * 64 + (((lane >> 4) ^ ((rB >> 1) & 3)) * 16);

  GLOAD(smA + 0 + ldsW, aS);             GLOAD(smB + 0 + ldsW, bS);
  GLOAD(smA + 16384 + ldsW, aS + 8192);  GLOAD(smB + 16384 + ldsW, bS + 8192);
  GLOAD(smA + 32768 + ldsW, aS + 16384); GLOAD(smB + 32768 + ldsW, bS + 16384);
  asm volatile("s_waitcnt vmcnt(4)" ::: "memory");
  __builtin_amdgcn_s_barrier();

  for (int t = 0; t < NT; ++t){
    const int cur = (t & 3) * 16384;
    const int stb = ((t + 3) & 3) * 16384;
    const size_t ko = (size_t)(t + 3) * 8192;
    if (t + 3 < NT){ GLOAD(smA + stb + ldsW, aS + ko); GLOAD(smB + stb + ldsW, bS + ko); }
    short8 a[4], bb[4];
    #pragma unroll
    for (int ni = 0; ni < 4; ni++)
      bb[ni] = *(const short8*)(smB + cur + bbase + ni * 1024);
    #pragma unroll
    for (int q = 0; q < 4; q++)
      a[q] = *(const short8*)(smA + cur + abase + q * 1024);
    #pragma unroll
    for (int q = 0; q < 4; q++)
      #pragma unroll
      for (int ni = 0; ni < 4; ni++)
        acc[q][ni] = MFMA16(a[q], bb[ni], acc[q][ni], 0, 0, 0);
    if      (t + 3 < NT) asm volatile("s_waitcnt vmcnt(4)" ::: "memory");
    else if (t + 2 < NT) asm volatile("s_waitcnt vmcnt(2)" ::: "memory");
    else if (t + 1 < NT) asm volatile("s_waitcnt vmcnt(0)" ::: "memory");
    __builtin_amdgcn_s_barrier();
  }

  #pragma unroll
  for (int mi = 0; mi < 4; mi++){
    if (EPI == 3){
      #pragma unroll
      for (int p = 0; p < 2; p++)
        #pragma unroll
        for (int v = 0; v < 4; v++){
          int row = (int)(tm + wm * 64 + mi * 16 + (lane >> 4) * 4 + v);
          int col = (int)((tn >> 1) + wn * 32 + p * 16 + (lane & 15));
          float u = acc[mi][2*p][v], g = acc[mi][2*p+1][v];
          Cbf[pidx(row, col, 1408)] = f2bf(u * g * gelu_phi(g));
        }
    } else {
      #pragma unroll
      for (int ni = 0; ni < 4; ni++)
        #pragma unroll
        for (int v = 0; v < 4; v++){
          int row = (int)(tm + wm * 64 + mi * 16 + (lane >> 4) * 4 + v);
          int col = (int)(tn + wn * 64 + ni * 16 + (lane & 15));
          float x = acc[mi][ni][v];
          if (EPI == 4){
            int hd = col >> 6, d = col & 63;
            Cbf[((size_t)hd * 32768 + row) * 64 + d] = f2bf(x);
          } else if (EPI == 1){
            Cres[(long)row * 512 + col] = x + Cres[(long)row * 512 + col];
          } else {
            float rr = x + Cres[(long)row * 512 + col];
            Cres[(long)row * 512 + col] = rr;
            Cbf[pidx(row, col, 512)] = f2bf(rr);
          }
        }
    }
  }
}

// ---------------- local attention (R14/R16 verified best: single-window, XCD-grouped) ----
__global__ __launch_bounds__(256, 2)
void attn_kernel(const short* __restrict__ qkv, short* __restrict__ o)
{
  __shared__ short Ks[128 * 64];
  __shared__ short Vt[64 * 136];
  __shared__ short Ps[4 * 32 * 128];
  char* smK = (char*)Ks;
  const int fdec = (blockIdx.x & 7) * 256 + (blockIdx.x >> 3);
  const int win = fdec & 31, hh = (fdec >> 5) & 7, b = fdec >> 8;
  const int tid = threadIdx.x, lane = tid & 63, w = tid >> 6;
  const long qrow0 = (long)b * 4096 + (long)win * 128;
  const short* Qb = qkv + (size_t)hh * 2097152;
  const short* Kb = qkv + (size_t)(8 + hh) * 2097152;
  const short* Vb = qkv + (size_t)(16 + hh) * 2097152;

  short8 qf[2][2];
  #pragma unroll
  for (int i = 0; i < 2; i++)
    #pragma unroll
    for (int kk = 0; kk < 2; kk++)
      qf[i][kk] = *(const short8*)(Qb + (qrow0 + w * 32 + i * 16 + (lane & 15)) * 64
                                   + kk * 32 + (lane >> 4) * 8);

  f32x4 oacc[2][4];
  #pragma unroll
  for (int i = 0; i < 2; i++)
    #pragma unroll
    for (int j = 0; j < 4; j++) oacc[i][j] = (f32x4){0.f,0.f,0.f,0.f};
  float rs[2][4];
  #pragma unroll
  for (int i = 0; i < 2; i++)
    #pragma unroll
    for (int v = 0; v < 4; v++) rs[i][v] = 0.f;

  const int row_s = tid >> 3;
  const int c_s   = tid & 7;
  const int schK  = (tid & 7) ^ ((tid >> 3) & 7);
  for (int cc = 0; cc < 3; cc++){
    int kw = win - 1 + cc;
    if (kw < 0 || kw >= 32) continue;
    const long krow0 = (long)b * 4096 + (long)kw * 128;
    __syncthreads();
    const short* srcK = Kb + (krow0 + row_s) * 64 + schK * 8;
    const short* srcV = Vb + (krow0 + row_s) * 64 + c_s * 8;
    #pragma unroll
    for (int r = 0; r < 4; r++){
      GLOAD(smK + w * 1024 + r * 4096, srcK + (size_t)r * 32 * 64);
      short8 vv = *(const short8*)(srcV + (size_t)r * 32 * 64);
      int row = row_s + r * 32;
      #pragma unroll
      for (int e = 0; e < 8; e++) Vt[(c_s * 8 + e) * 136 + row] = vv[e];
    }
    __syncthreads();

    f32x4 sacc[2][8];
    #pragma unroll
    for (int i = 0; i < 2; i++)
      #pragma unroll
      for (int j = 0; j < 8; j++) sacc[i][j] = (f32x4){0.f,0.f,0.f,0.f};
    #pragma unroll
    for (int kk = 0; kk < 2; kk++){
      short8 bbk[8];
      int ac = (kk * 32 + (lane >> 4) * 8) * 2;
      #pragma unroll
      for (int j = 0; j < 8; j++){
        int br = j * 16 + (lane & 15);
        bbk[j] = *(const short8*)((char*)Ks + ((br * 128 + ac) ^ ((br & 7) << 4)));
      }
      #pragma unroll
      for (int i = 0; i < 2; i++)
        #pragma unroll
        for (int j = 0; j < 8; j++)
          sacc[i][j] = MFMA16(qf[i][kk], bbk[j], sacc[i][j], 0, 0, 0);
    }

    short* myPs = Ps + w * 32 * 128;
    float psum[2][4];
    #pragma unroll
    for (int i = 0; i < 2; i++)
      #pragma unroll
      for (int v = 0; v < 4; v++) psum[i][v] = 0.f;
    #pragma unroll
    for (int i = 0; i < 2; i++)
      #pragma unroll
      for (int j = 0; j < 8; j++)
        #pragma unroll
        for (int v = 0; v < 4; v++){
          float p = __expf(0.125f * sacc[i][j][v]);
          psum[i][v] += p;
          int prow = i * 16 + (lane >> 4) * 4 + v;
          int pcb  = (j * 16 + (lane & 15)) * 2;
          *(short*)((char*)myPs + ((prow * 256 + pcb) ^ ((prow & 7) << 4))) = f2bf(p);
        }
    #pragma unroll
    for (int i = 0; i < 2; i++)
      #pragma unroll
      for (int v = 0; v < 4; v++){
        float s = psum[i][v];
        s += __shfl_xor(s, 1); s += __shfl_xor(s, 2);
        s += __shfl_xor(s, 4); s += __shfl_xor(s, 8);
        rs[i][v] += s;
      }
    __syncthreads();

    #pragma unroll
    for (int kk = 0; kk < 4; kk++){
      short8 pa[2], vb[4];
      int kb = (kk * 32 + (lane >> 4) * 8) * 2;
      #pragma unroll
      for (int i = 0; i < 2; i++){
        int pr = i * 16 + (lane & 15);
        pa[i] = *(const short8*)((char*)myPs + ((pr * 256 + kb) ^ ((pr & 7) << 4)));
      }
      #pragma unroll
      for (int j = 0; j < 4; j++){
        int vr = j * 16 + (lane & 15);
        vb[j] = *(const short8*)((char*)Vt + (vr * 272 + kb));
      }
      #pragma unroll
      for (int i = 0; i < 2; i++)
        #pragma unroll
        for (int j = 0; j < 4; j++)
          oacc[i][j] = MFMA16(pa[i], vb[j], oacc[i][j], 0, 0, 0);
    }
  }

  #pragma unroll
  for (int i = 0; i < 2; i++)
    #pragma unroll
    for (int j = 0; j < 4; j++)
      #pragma unroll
      for (int v = 0; v < 4; v++){
        int row = (int)(qrow0 + w * 32 + i * 16 + (lane >> 4) * 4 + v);
        int col = hh * 64 + j * 16 + (lane & 15);
        o[pidx(row, col, 512)] = f2bf(oacc[i][j][v] / rs[i][v]);
      }
}

// ---------------- layernorm (packed bf16 out) ----------------
__global__ __launch_bounds__(256)
void ln_kernel(const float* __restrict__ h, const float* __restrict__ g,
               const float* __restrict__ be, short* __restrict__ y)
{
  long row = (long)blockIdx.x * 4 + (threadIdx.x >> 6);
  int lane = threadIdx.x & 63;
  const float* x = h + row * 512 + lane * 8;
  float4 a0 = *(const float4*)x;
  float4 a1 = *(const float4*)(x + 4);
  float v[8] = {a0.x, a0.y, a0.z, a0.w, a1.x, a1.y, a1.z, a1.w};
  float s = 0.f, sq = 0.f;
  #pragma unroll
  for (int j = 0; j < 8; j++){ s += v[j]; sq += v[j] * v[j]; }
  #pragma unroll
  for (int m = 1; m <= 32; m <<= 1){ s += __shfl_xor(s, m); sq += __shfl_xor(sq, m); }
  float mu = s * (1.f / 512.f);
  float var = sq * (1.f / 512.f) - mu * mu;
  float rstd = rsqrtf(var + 1e-5f);
  short8 yv;
  #pragma unroll
  for (int j = 0; j < 8; j++){
    int c = lane * 8 + j;
    yv[j] = f2bf((v[j] - mu) * rstd * g[c] + be[c]);
  }
  *(short8*)(y + pidx((int)row, lane * 8, 512)) = yv;
}

// ---------------- mean pool + classifier ----------------
__global__ void pool_partial(const float* __restrict__ h, float* __restrict__ part){
  int b = blockIdx.x, ch = blockIdx.y, t = threadIdx.x;
  float s0 = 0.f, s1 = 0.f;
  const float* base = h + ((long)b * 4096 + ch * 128) * 512;
  for (int n = 0; n < 128; n++){
    s0 += base[(long)n * 512 + t];
    s1 += base[(long)n * 512 + t + 256];
  }
  part[((b * 32 + ch) * 512) + t] = s0;
  part[((b * 32 + ch) * 512) + t + 256] = s1;
}

__global__ void pool_proj(const float* __restrict__ part, const float* __restrict__ pw,
                          const float* __restrict__ pb, float* __restrict__ out){
  __shared__ float pooled[512];
  __shared__ float red[4];
  int b = blockIdx.x, t = threadIdx.x;
  int lane = t & 63, w = t >> 6;
  float s0 = 0.f, s1 = 0.f;
  for (int ch = 0; ch < 32; ch++){
    s0 += part[((b * 32 + ch) * 512) + t];
    s1 += part[((b * 32 + ch) * 512) + t + 256];
  }
  pooled[t] = s0 * (1.f / 4096.f);
  pooled[t + 256] = s1 * (1.f / 4096.f);
  __syncthreads();
  for (int cls = 0; cls < 10; cls++){
    float p = pooled[t] * pw[cls * 512 + t] + pooled[t + 256] * pw[cls * 512 + t + 256];
    p += __shfl_xor(p, 1); p += __shfl_xor(p, 2); p += __shfl_xor(p, 4);
    p += __shfl_xor(p, 8); p += __shfl_xor(p, 16); p += __shfl_xor(p, 32);
    if (lane == 0) red[w] = p;
    __syncthreads();
    if (t == 0) out[b * 10 + cls] = red[0] + red[1] + red[2] + red[3] + pb[cls];
    __syncthreads();
  }
}

extern "C" void kernel_launch(void* const* d_in, const int* in_sizes, int n_in,
                              void* d_out, int out_size, void* d_ws, size_t ws_size,
                              hipStream_t stream)
{
  const float* x      = (const float*)d_in[0];
  const float* lin_w  = (const float*)d_in[1];
  const float* lin_b  = (const float*)d_in[2];
  const float* qkvw_f = (const float*)d_in[3];
  const float* outw_f = (const float*)d_in[4];
  const float* lng    = (const float*)d_in[5];
  const float* lnb    = (const float*)d_in[6];
  const float* w1_f   = (const float*)d_in[7];
  const float* w2_f   = (const float*)d_in[8];
  const float* projw  = (const float*)d_in[9];
  const float* projb  = (const float*)d_in[10];
  float* out = (float*)d_out;

  char* ws = (char*)d_ws;
  float* hf32 = (float*)(ws);
  short* abuf = (short*)(ws + 67108864);
  short* qkvb = (short*)(ws + 100663296);
  short* gbuf = qkvb;
  short* obuf = (short*)(ws + 201326592);
  float* part = (float*)(ws + 234881024);
  short* wqkv = (short*)(ws + 235405312);
  short* wout = (short*)(ws + 247988224);
  short* w1p  = (short*)(ws + 250085376);
  short* w2p  = (short*)(ws + 261619712);

  cast_pack_kernel<<<3072, 256, 0, stream>>>(qkvw_f, wqkv, 1536, 512);
  cast_pack_kernel<<<1024, 256, 0, stream>>>(outw_f, wout, 512, 512);
  w1p_kernel<<<5632, 256, 0, stream>>>(w1_f, w1p);
  w2p_kernel<<<2816, 256, 0, stream>>>(w2_f, w2p);
  embed_kernel<<<8192, 256, 0, stream>>>(x, lin_w, lin_b, hf32, abuf);

  for (int l = 0; l < 4; l++){
    gemm_pk<4><<<dim3(6, 128), 1024, 0, stream>>>(abuf, wqkv + (size_t)l * 1536 * 512, 512,
                                                  nullptr, qkvb, 0);
    attn_kernel<<<2048, 256, 0, stream>>>(qkvb, obuf);
    gemm_pk<1><<<dim3(2, 128), 1024, 0, stream>>>(obuf, wout + (size_t)l * 512 * 512, 512,
                                                  hf32, nullptr, 0);
    ln_kernel<<<8192, 256, 0, stream>>>(hf32, lng + l * 512, lnb + l * 512, abuf);
    gemm_pk<3><<<dim3(11, 128), 1024, 0, stream>>>(abuf, w1p + (size_t)l * 2816 * 512, 512,
                                                   nullptr, gbuf, 1408);
    gemm_pk<2><<<dim3(2, 128), 1024, 0, stream>>>(gbuf, w2p + (size_t)l * 512 * 1408, 1408,
                                                  hf32, abuf, 512);
  }
  pool_partial<<<dim3(8, 32), 256, 0, stream>>>(hf32, part);
  pool_proj<<<8, 256, 0, stream>>>(part, projw, projb, out);
}